// Round 1
// 244.009 us; speedup vs baseline: 1.0408x; 1.0408x over previous
//
#include <hip/hip_runtime.h>

#define N_NODES 100000
#define N_EDGES 1600000
#define D 64
#define CAP 32         // slot cap per node; Poisson(16): P(deg>32)~1e-5/node, ovf backstops
#define OVF_CAP 8192   // overflow edge list (backstop)
#define N_TILES 1563   // (N_NODES + 63) / 64
#define NR 8           // region groups (dst>>14 -> 0..6; r==7 blocks do emb->bf16 cvt)
#define SLICE_EDGES 2048
#define N_SLICES 782   // ceil(N_EDGES / SLICE_EDGES)
#define R1_BLOCKS 64   // stage-1 reduce blocks
#define R1_ROWS 25     // ceil(N_TILES / R1_BLOCKS)
#define ASTRIDE 136    // LDS row stride in bf16 elems (128 + 8 pad, 16B-aligned)

typedef int    vint4  __attribute__((ext_vector_type(4)));
typedef short  s16x4  __attribute__((ext_vector_type(4)));
typedef short  s16x8  __attribute__((ext_vector_type(8)));
typedef float  f32x4  __attribute__((ext_vector_type(4)));
typedef __bf16 bf16x8 __attribute__((ext_vector_type(8)));  // MFMA operand type

// f32 -> bf16 (RNE). Inputs are finite; NaN path not needed.
__device__ inline short f2bf(float f) {
    unsigned u = __builtin_bit_cast(unsigned, f);
    u += 0x7fffu + ((u >> 16) & 1u);
    return (short)(u >> 16);
}
__device__ inline s16x4 f2bf4(float4 v) {
    s16x4 r; r.x = f2bf(v.x); r.y = f2bf(v.y); r.z = f2bf(v.z); r.w = f2bf(v.w);
    return r;
}
__device__ inline float bf2f(short s) {
    return __builtin_bit_cast(float, ((unsigned)(unsigned short)s) << 16);
}

// ws layout (bytes):
//   cnt    @ 0        : N_NODES int           (0.4 MB)
//   slots  @ 401408   : N_NODES*CAP int       (12.8 MB)
//   acc    @ 13201408 : N_NODES*D float       (25.6 MB)
//   ovfc   @ 38801408 : int
//   ovf    @ 38801424 : OVF_CAP int2
//   part   @ 38867200 : N_TILES*64 float      (0.4 MB)
//   part2  @ 39267328 : R1_BLOCKS*64 float    (16 KB)
//   emb16  @ 39283712 : N_NODES*D bf16        (12.8 MB, optional tier)
#define WS_SLOTS_OFF 401408
#define WS_ACC_OFF   13201408
#define WS_OVFC_OFF  38801408
#define WS_OVF_OFF   38801424
#define WS_PART_OFF  38867200
#define WS_PART2_OFF 39267328
#define WS_EMB16_OFF 39283712
#define WS_NEEDED    (WS_PART2_OFF + R1_BLOCKS * 64 * 4)
#define WS_NEEDED16  (WS_EMB16_OFF + N_NODES * D * 2)

// ---------------------------------------------------------------------------
// Region-partitioned CSR fill (R8-proven), ILP-restructured (R10):
// Phase A issues ALL 8 region-filtered atomicAdds back-to-back (independent,
// co-issued -> one atomic round-trip of latency instead of eight dependent
// ones); phase B does the slot stores (progressive vmcnt waits, ~free);
// phase C handles the rare overflow. The old per-iteration
// atomic->wait(pos)->store chain was ~8x serialized per wave and is why the
// counters showed 82us at 3% VALU / 18% HBM (pure latency).
// r==7 blocks (previously idle) convert emb f32->bf16 for the gather,
// riding fill's idle bandwidth.
// ---------------------------------------------------------------------------
__global__ __launch_bounds__(256) void fill_kernel(
    const int* __restrict__ edge_src, const int* __restrict__ edge_dst,
    int* __restrict__ cnt, int* __restrict__ slots,
    int* __restrict__ ovf_cnt, int2* __restrict__ ovf,
    const float* __restrict__ emb, short* __restrict__ emb16) {
    const int r = blockIdx.x & (NR - 1);
    const int slice = blockIdx.x >> 3;
    if (r == 7) {
        if (emb16) {
            const float4* e4 = (const float4*)emb;
            for (int t = slice * 256 + threadIdx.x; t < N_NODES * D / 8;
                 t += N_SLICES * 256) {
                float4 a = e4[t * 2];
                float4 b = e4[t * 2 + 1];
                s16x4 lo = f2bf4(a), hi = f2bf4(b);
                s16x8 pk = {lo.x, lo.y, lo.z, lo.w, hi.x, hi.y, hi.z, hi.w};
                *(s16x8*)&emb16[t * 8] = pk;
            }
        }
        return;
    }
    const int base_e = slice * SLICE_EDGES + threadIdx.x * 8;
    if (base_e >= N_EDGES) return;
    const vint4* s4 = (const vint4*)(edge_src + base_e);
    const vint4* d4 = (const vint4*)(edge_dst + base_e);
    vint4 a0 = __builtin_nontemporal_load(s4);
    vint4 a1 = __builtin_nontemporal_load(s4 + 1);
    vint4 b0 = __builtin_nontemporal_load(d4);
    vint4 b1 = __builtin_nontemporal_load(d4 + 1);
    int ss[8] = {a0.x, a0.y, a0.z, a0.w, a1.x, a1.y, a1.z, a1.w};
    int dd[8] = {b0.x, b0.y, b0.z, b0.w, b1.x, b1.y, b1.z, b1.w};
    // Phase A: co-issue all atomics (independent; latency overlaps).
    int pos[8];
#pragma unroll
    for (int i = 0; i < 8; ++i) {
        pos[i] = ((dd[i] >> 14) == r) ? atomicAdd(&cnt[dd[i]], 1) : -1;
    }
    // Phase B: slot stores (waits are progressive vmcnt, ~free).
#pragma unroll
    for (int i = 0; i < 8; ++i) {
        if (pos[i] >= 0 && pos[i] < CAP) slots[dd[i] * CAP + pos[i]] = ss[i];
    }
    // Phase C: rare overflow backstop.
#pragma unroll
    for (int i = 0; i < 8; ++i) {
        if (pos[i] >= CAP) {
            int j = atomicAdd(ovf_cnt, 1);
            if (j < OVF_CAP) ovf[j] = make_int2(ss[i], dd[i]);
        }
    }
}

// ---------------------------------------------------------------------------
// Atomic-free gather, bf16 emb (R10): halves the random emb read traffic
// (1.6M x 128B instead of 256B) and fits the table in 12.8MB (L2-friendlier).
// One wave per node; q=lane>>4 picks slot e+q, c=lane&15 picks a 4-elem
// column chunk; butterfly over q; q==0 stores f32 acc (layout unchanged,
// final_kernel untouched).
// ---------------------------------------------------------------------------
__global__ __launch_bounds__(256) void gather16_kernel(
    const short* __restrict__ emb16, const int* __restrict__ cnt,
    const int* __restrict__ slots, float* __restrict__ acc) {
    const int lane = threadIdx.x & 63;
    const int wave = threadIdx.x >> 6;
    const int v = blockIdx.x * 4 + wave;
    const int q = lane >> 4;
    const int c = lane & 15;
    int deg = cnt[v];
    if (deg > CAP) deg = CAP;
    const int si = slots[v * CAP + (lane & (CAP - 1))];

    float4 sum = make_float4(0.f, 0.f, 0.f, 0.f);
    for (int e = 0; e < deg; e += 4) {
        const int idx = e + q;
        const int s = __shfl(si, idx & (CAP - 1));
        if (idx < deg) {
            s16x4 a = *(const s16x4*)&emb16[s * D + c * 4];
            sum.x += bf2f(a.x);
            sum.y += bf2f(a.y);
            sum.z += bf2f(a.z);
            sum.w += bf2f(a.w);
        }
    }
#pragma unroll
    for (int off = 16; off < 64; off <<= 1) {
        sum.x += __shfl_xor(sum.x, off);
        sum.y += __shfl_xor(sum.y, off);
        sum.z += __shfl_xor(sum.z, off);
        sum.w += __shfl_xor(sum.w, off);
    }
    if (q == 0) {
        ((float4*)acc)[v * 16 + c] = sum;
    }
}

// f32 fallback gather (mid tier, ws too small for emb16).
__global__ __launch_bounds__(256) void gather_kernel(
    const float* __restrict__ emb, const int* __restrict__ cnt,
    const int* __restrict__ slots, float* __restrict__ acc) {
    const int lane = threadIdx.x & 63;
    const int wave = threadIdx.x >> 6;
    const int v = blockIdx.x * 4 + wave;
    const int q  = lane >> 4;
    const int c4 = lane & 15;
    int deg = cnt[v];
    if (deg > CAP) deg = CAP;
    const int si = slots[v * CAP + (lane & (CAP - 1))];
    const float4* emb4 = (const float4*)emb;

    float4 sum = make_float4(0.f, 0.f, 0.f, 0.f);
    for (int e = 0; e < deg; e += 4) {
        const int idx = e + q;
        const int s = __shfl(si, idx & (CAP - 1));
        if (idx < deg) {
            float4 a = emb4[s * 16 + c4];
            sum.x += a.x; sum.y += a.y; sum.z += a.z; sum.w += a.w;
        }
    }
#pragma unroll
    for (int off = 16; off < 64; off <<= 1) {
        sum.x += __shfl_xor(sum.x, off);
        sum.y += __shfl_xor(sum.y, off);
        sum.z += __shfl_xor(sum.z, off);
        sum.w += __shfl_xor(sum.w, off);
    }
    if (q == 0) {
        ((float4*)acc)[v * 16 + c4] = sum;
    }
}

// Overflow edges (a handful at CAP=32): parallel, adds into acc AFTER gather.
__global__ __launch_bounds__(256) void ovf_kernel(
    const float* __restrict__ emb, const int* __restrict__ ovf_cnt,
    const int2* __restrict__ ovf, float* __restrict__ acc) {
    int n = *ovf_cnt;
    if (n > OVF_CAP) n = OVF_CAP;
    const int lane = threadIdx.x & 63;
    const int wv = (blockIdx.x * 256 + threadIdx.x) >> 6;
    const int nwaves = (gridDim.x * 256) >> 6;
    for (int i = wv; i < n; i += nwaves) {
        int2 e = ovf[i];
        unsafeAtomicAdd(&acc[e.y * D + lane], emb[e.x * D + lane]);
    }
}

// Fallback scatter (only if ws too small).
__global__ __launch_bounds__(256) void scatter_kernel(
    const float* __restrict__ emb,
    const int* __restrict__ edge_src, const int* __restrict__ edge_dst,
    float* __restrict__ acc) {
    int gid = blockIdx.x * 256 + threadIdx.x;
    int e = gid >> 6;
    int c = gid & 63;
    unsafeAtomicAdd(&acc[edge_dst[e] * D + c], emb[edge_src[e] * D + c]);
}

// ---------------------------------------------------------------------------
// Final pass, MFMA. z = [feat|nbr] @ [W1|W2]^T, K=128, mfma_f32_16x16x32_bf16
// (4 k-steps). W fragments hoisted into 64 VGPRs once per block; per 16-node
// strip a wave issues 4 A-frag reads + 16 MFMAs. Fragment layouts
// (m89/m120-verified): a-operand A[m=lane&15][k=quad*8+j] -> m is D's ROW;
// b-operand B[n=lane&15][k] -> n is D's COL; C/D col=lane&15, row=quad*4+reg.
// Bias+ReLU in C-layout, masked for the ragged tail tile, then shfl+LDS
// reduce -> per-block partials.
// ---------------------------------------------------------------------------
__global__ __launch_bounds__(256) void final_kernel(
    const float* __restrict__ feat, const float* __restrict__ acc,
    const float* __restrict__ W1, const float* __restrict__ b1,
    const float* __restrict__ W2, const float* __restrict__ b2,
    float* __restrict__ partials) {
    __shared__ short A_s[64 * ASTRIDE];  // [node][feat(0..63)|nbr(64..127)] bf16
    __shared__ short W_s[64 * ASTRIDE];  // [o][W1(0..63)|W2(64..127)] bf16
    __shared__ float red[4][64];

    const int tid  = threadIdx.x;
    const int lane = tid & 63;
    const int wave = tid >> 6;
    const int quad = lane >> 4;
    const int col  = lane & 15;
    const int node0 = blockIdx.x * 64;

    // Per-lane bias for output o = nb*16 + col (col == C/D column index).
    float bias[4];
#pragma unroll
    for (int nb = 0; nb < 4; ++nb) {
        const int o = nb * 16 + col;
        bias[nb] = b1[o] + b2[o];
    }

    // Stage W (bf16): 1024 float4 per matrix, 4 per thread, coalesced.
    {
        const float4* W1v = (const float4*)W1;
        const float4* W2v = (const float4*)W2;
#pragma unroll
        for (int i = 0; i < 4; ++i) {
            const int flat = tid + i * 256;   // 0..1023
            const int row = flat >> 4, c4 = flat & 15;
            *(s16x4*)&W_s[row * ASTRIDE + c4 * 4]      = f2bf4(W1v[flat]);
            *(s16x4*)&W_s[row * ASTRIDE + 64 + c4 * 4] = f2bf4(W2v[flat]);
        }
    }

    // Stage A tile (bf16): feat + nbr rows for nodes node0..node0+63.
    {
        const float4* fv = (const float4*)feat;
        const float4* av = (const float4*)acc;
#pragma unroll
        for (int i = 0; i < 4; ++i) {
            const int flat = tid + i * 256;
            const int row = flat >> 4, c4 = flat & 15;
            const int node = node0 + row;
            float4 f = make_float4(0.f, 0.f, 0.f, 0.f);
            float4 n = make_float4(0.f, 0.f, 0.f, 0.f);
            if (node < N_NODES) {
                f = fv[(size_t)node * 16 + c4];
                n = av[(size_t)node * 16 + c4];
            }
            *(s16x4*)&A_s[row * ASTRIDE + c4 * 4]      = f2bf4(f);
            *(s16x4*)&A_s[row * ASTRIDE + 64 + c4 * 4] = f2bf4(n);
        }
    }
    __syncthreads();

    // Hoist all 16 B-fragments (4 output-blocks x 4 k-steps) into VGPRs.
    bf16x8 Bf[4][4];
#pragma unroll
    for (int nb = 0; nb < 4; ++nb)
#pragma unroll
        for (int ks = 0; ks < 4; ++ks)
            Bf[nb][ks] = __builtin_bit_cast(bf16x8,
                *(const s16x8*)&W_s[(nb * 16 + col) * ASTRIDE + ks * 32 + quad * 8]);

    // This wave's 16-node strip x 64 outputs: 4 A reads + 16 MFMAs.
    f32x4 C[4];
#pragma unroll
    for (int nb = 0; nb < 4; ++nb) C[nb] = (f32x4){0.f, 0.f, 0.f, 0.f};
#pragma unroll
    for (int ks = 0; ks < 4; ++ks) {
        const bf16x8 Af = __builtin_bit_cast(bf16x8,
            *(const s16x8*)&A_s[(wave * 16 + col) * ASTRIDE + ks * 32 + quad * 8]);
#pragma unroll
        for (int nb = 0; nb < 4; ++nb)
            C[nb] = __builtin_amdgcn_mfma_f32_16x16x32_bf16(Af, Bf[nb][ks],
                                                            C[nb], 0, 0, 0);
    }

    // Epilogue: bias + ReLU per element (C-layout), mask OOB nodes, column
    // sums via shfl over quads, cross-wave combine in LDS.
    float sums[4] = {0.f, 0.f, 0.f, 0.f};
#pragma unroll
    for (int nb = 0; nb < 4; ++nb) {
#pragma unroll
        for (int reg = 0; reg < 4; ++reg) {
            const int node = node0 + wave * 16 + quad * 4 + reg;
            float u = C[nb][reg] + bias[nb];
            u = (u > 0.f) ? u : 0.f;
            if (node < N_NODES) sums[nb] += u;
        }
        sums[nb] += __shfl_xor(sums[nb], 16);
        sums[nb] += __shfl_xor(sums[nb], 32);
        if (lane < 16) red[wave][nb * 16 + lane] = sums[nb];
    }
    __syncthreads();
    if (tid < 64) {
        partials[blockIdx.x * 64 + tid] =
            red[0][tid] + red[1][tid] + red[2][tid] + red[3][tid];
    }
}

// ---------------------------------------------------------------------------
// Two-stage partials reduction (R9-proven; single-block version was 110us).
// ---------------------------------------------------------------------------
__global__ __launch_bounds__(256) void reduce1_kernel(
    const float* __restrict__ partials, float* __restrict__ part2) {
    __shared__ float red[4][64];
    const int col = threadIdx.x & 63;
    const int seg = threadIdx.x >> 6;
    const int r0 = blockIdx.x * R1_ROWS;
    int r1 = r0 + R1_ROWS;
    if (r1 > N_TILES) r1 = N_TILES;
    float s = 0.f;
    for (int r = r0 + seg; r < r1; r += 4) s += partials[r * 64 + col];
    red[seg][col] = s;
    __syncthreads();
    if (seg == 0) {
        part2[blockIdx.x * 64 + col] =
            red[0][col] + red[1][col] + red[2][col] + red[3][col];
    }
}

__global__ __launch_bounds__(256) void reduce2_kernel(
    const float* __restrict__ part2, float* __restrict__ out) {
    __shared__ float red[4][64];
    const int col = threadIdx.x & 63;
    const int seg = threadIdx.x >> 6;
    float s = 0.f;
    for (int r = seg; r < R1_BLOCKS; r += 4) s += part2[r * 64 + col];
    red[seg][col] = s;
    __syncthreads();
    if (seg == 0) {
        out[col] = red[0][col] + red[1][col] + red[2][col] + red[3][col];
    }
}

extern "C" void kernel_launch(void* const* d_in, const int* in_sizes, int n_in,
                              void* d_out, int out_size, void* d_ws, size_t ws_size,
                              hipStream_t stream) {
    const float* feat = (const float*)d_in[0];
    const float* emb  = (const float*)d_in[1];
    const float* W1   = (const float*)d_in[2];
    const float* b1   = (const float*)d_in[3];
    const float* W2   = (const float*)d_in[4];
    const float* b2   = (const float*)d_in[5];
    const int* edge_src = (const int*)d_in[6];
    const int* edge_dst = (const int*)d_in[7];
    float* out = (float*)d_out;
    char* ws = (char*)d_ws;

    if (ws_size >= (size_t)WS_NEEDED) {
        int*   cnt      = (int*)ws;
        int*   slots    = (int*)(ws + WS_SLOTS_OFF);
        float* acc      = (float*)(ws + WS_ACC_OFF);
        int*   ovf_cnt  = (int*)(ws + WS_OVFC_OFF);
        int2*  ovf      = (int2*)(ws + WS_OVF_OFF);
        float* partials = (float*)(ws + WS_PART_OFF);
        float* part2    = (float*)(ws + WS_PART2_OFF);
        short* emb16    = (ws_size >= (size_t)WS_NEEDED16)
                              ? (short*)(ws + WS_EMB16_OFF) : (short*)0;

        (void)hipMemsetAsync(cnt, 0, N_NODES * sizeof(int), stream);
        (void)hipMemsetAsync(ovf_cnt, 0, sizeof(int), stream);

        fill_kernel<<<NR * N_SLICES, 256, 0, stream>>>(edge_src, edge_dst,
                                                       cnt, slots, ovf_cnt, ovf,
                                                       emb, emb16);
        if (emb16) {
            gather16_kernel<<<N_NODES / 4, 256, 0, stream>>>(emb16, cnt, slots, acc);
        } else {
            gather_kernel<<<N_NODES / 4, 256, 0, stream>>>(emb, cnt, slots, acc);
        }
        ovf_kernel<<<16, 256, 0, stream>>>(emb, ovf_cnt, ovf, acc);

        final_kernel<<<N_TILES, 256, 0, stream>>>(feat, acc, W1, b1, W2, b2,
                                                  partials);
        reduce1_kernel<<<R1_BLOCKS, 256, 0, stream>>>(partials, part2);
        reduce2_kernel<<<1, 256, 0, stream>>>(part2, out);
    } else {
        // Fallback: atomic scatter (correct but slow).
        float* acc = (float*)ws;
        (void)hipMemsetAsync(acc, 0, (size_t)N_NODES * D * sizeof(float), stream);
        scatter_kernel<<<(N_EDGES * 64) / 256, 256, 0, stream>>>(emb, edge_src,
                                                                 edge_dst, acc);
        float* partials = (float*)(ws + (size_t)N_NODES * D * sizeof(float));
        float* part2    = partials + (size_t)N_TILES * 64;
        final_kernel<<<N_TILES, 256, 0, stream>>>(feat, acc, W1, b1, W2, b2,
                                                  partials);
        reduce1_kernel<<<R1_BLOCKS, 256, 0, stream>>>(partials, part2);
        reduce2_kernel<<<1, 256, 0, stream>>>(part2, out);
    }
}

// Round 2
// 198.732 us; speedup vs baseline: 1.2779x; 1.2278x over previous
//
#include <hip/hip_runtime.h>

#define N_NODES 100000
#define N_EDGES 1600000
#define D 64
#define CAP 32         // slot cap per node; Poisson(16): P(deg>32)~1e-5/node, ovf backstops
#define OVF_CAP 8192   // overflow edge list (backstop)
#define N_TILES 1563   // (N_NODES + 63) / 64
#define NR 8           // (legacy fill) region groups
#define SLICE_EDGES 2048
#define N_SLICES 782   // ceil(N_EDGES / SLICE_EDGES)
#define R1_BLOCKS 64   // stage-1 reduce blocks
#define R1_ROWS 25     // ceil(N_TILES / R1_BLOCKS)
#define ASTRIDE 136    // LDS row stride in bf16 elems (128 + 8 pad, 16B-aligned)

// Bucketed partition (R11)
#define NB 391         // ceil(N_NODES/256) buckets of 256 nodes
#define BCAP 4608      // per-bucket edge capacity (mean 4092, sigma~64 -> +8 sigma)
#define EPB 8192       // edges per partition block
#define P1_BLOCKS 196  // ceil(N_EDGES / EPB)
#define CVT_BLOCKS 64  // extra part_kernel blocks doing emb f32->bf16

typedef int    vint4  __attribute__((ext_vector_type(4)));
typedef short  s16x4  __attribute__((ext_vector_type(4)));
typedef short  s16x8  __attribute__((ext_vector_type(8)));
typedef float  f32x4  __attribute__((ext_vector_type(4)));
typedef __bf16 bf16x8 __attribute__((ext_vector_type(8)));  // MFMA operand type

// f32 -> bf16 (RNE). Inputs are finite; NaN path not needed.
__device__ inline short f2bf(float f) {
    unsigned u = __builtin_bit_cast(unsigned, f);
    u += 0x7fffu + ((u >> 16) & 1u);
    return (short)(u >> 16);
}
__device__ inline s16x4 f2bf4(float4 v) {
    s16x4 r; r.x = f2bf(v.x); r.y = f2bf(v.y); r.z = f2bf(v.z); r.w = f2bf(v.w);
    return r;
}
__device__ inline float bf2f(short s) {
    return __builtin_bit_cast(float, ((unsigned)(unsigned short)s) << 16);
}

// ws layout (bytes):
//   cnt    @ 0        : N_NODES int           (0.4 MB)
//   slots  @ 401408   : N_NODES*CAP int       (12.8 MB)
//   acc    @ 13201408 : N_NODES*D float       (25.6 MB)   [bkt aliased here pre-gather]
//   ovfc   @ 38801408 : int
//   ovf    @ 38801424 : OVF_CAP int2
//   part   @ 38867200 : N_TILES*64 float      (0.4 MB)    [bcnt aliased here pre-final]
//   part2  @ 39267328 : R1_BLOCKS*64 float    (16 KB)
//   emb16  @ 39283712 : N_NODES*D bf16        (12.8 MB, optional tier)
#define WS_SLOTS_OFF 401408
#define WS_ACC_OFF   13201408
#define WS_OVFC_OFF  38801408
#define WS_OVF_OFF   38801424
#define WS_PART_OFF  38867200
#define WS_PART2_OFF 39267328
#define WS_EMB16_OFF 39283712
#define WS_NEEDED    (WS_PART2_OFF + R1_BLOCKS * 64 * 4)
#define WS_NEEDED16  (WS_EMB16_OFF + N_NODES * D * 2)

// ---------------------------------------------------------------------------
// R11 pass 1: edge partition into 391 dst-buckets. R10's atomic fill was
// bound by scattered-L2-transaction throughput (1.6M return-atomics on cnt
// spanning ~7K lines + 1.6M scattered 4B stores; VALU 4.5%, HBM 21%, nothing
// busy). Here each block reads its 8192-edge slice ONCE (vs 7x region
// re-read), bins in LDS (hist -> scan -> LDS-cursor scatter), reserves
// global bucket space with ONE atomicAdd per (block,bucket) (~77K total vs
// 1.6M), and writes compacted packed runs coalesced. pk = (src<<8)|dst_low8.
// Blocks >= P1_BLOCKS convert emb f32->bf16 (rides along as before).
// ---------------------------------------------------------------------------
__global__ __launch_bounds__(512) void part_kernel(
    const int* __restrict__ edge_src, const int* __restrict__ edge_dst,
    int* __restrict__ bcnt, int* __restrict__ bkt,
    int* __restrict__ ovf_cnt, int2* __restrict__ ovf,
    const float* __restrict__ emb, short* __restrict__ emb16) {
    const int tid = threadIdx.x;
    if (blockIdx.x >= P1_BLOCKS) {
        // emb f32 -> bf16 conversion, strided over the extra blocks.
        const float4* e4 = (const float4*)emb;
        const int t0 = (blockIdx.x - P1_BLOCKS) * 512 + tid;
        for (int t = t0; t < N_NODES * D / 8; t += CVT_BLOCKS * 512) {
            float4 a = e4[t * 2];
            float4 b = e4[t * 2 + 1];
            s16x4 lo = f2bf4(a), hi = f2bf4(b);
            s16x8 pk = {lo.x, lo.y, lo.z, lo.w, hi.x, hi.y, hi.z, hi.w};
            *(s16x8*)&emb16[t * 8] = pk;
        }
        return;
    }

    __shared__ int stage[EPB];       // packed edges, bucket-ordered
    __shared__ int sc[512];          // scan workspace
    __shared__ int hist[NB];
    __shared__ int startS[NB];
    __shared__ int cur[NB];
    __shared__ int gbase[NB];

    const int e0 = blockIdx.x * EPB;
    if (tid < NB) hist[tid] = 0;
    __syncthreads();

    // Load this thread's 16 edges (coalesced across the block per step).
    int ss[16], dd[16];
#pragma unroll
    for (int i = 0; i < 16; ++i) {
        const int e = e0 + i * 512 + tid;
        if (e < N_EDGES) {
            ss[i] = edge_src[e];
            dd[i] = edge_dst[e];
        } else {
            ss[i] = -1; dd[i] = -1;
        }
    }

    // Phase 1: histogram (LDS atomics).
#pragma unroll
    for (int i = 0; i < 16; ++i) {
        if (dd[i] >= 0) atomicAdd(&hist[dd[i] >> 8], 1);
    }
    __syncthreads();

    // Phase 2: inclusive scan over 512 slots (Hillis-Steele), then exclusive
    // starts + LDS cursors.
    sc[tid] = (tid < NB) ? hist[tid] : 0;
    __syncthreads();
    for (int off = 1; off < 512; off <<= 1) {
        int v = sc[tid];
        int add = (tid >= off) ? sc[tid - off] : 0;
        __syncthreads();
        sc[tid] = v + add;
        __syncthreads();
    }
    if (tid < NB) {
        const int st = sc[tid] - hist[tid];
        startS[tid] = st;
        cur[tid] = st;
    }
    __syncthreads();

    // Phase 3: scatter packed edges into bucket-ordered LDS staging.
#pragma unroll
    for (int i = 0; i < 16; ++i) {
        if (dd[i] >= 0) {
            const int b = dd[i] >> 8;
            const int pos = atomicAdd(&cur[b], 1);
            stage[pos] = (ss[i] << 8) | (dd[i] & 255);
        }
    }

    // Phase 4: reserve global bucket space (one atomic per block-bucket).
    if (tid < NB) gbase[tid] = atomicAdd(&bcnt[tid], hist[tid]);
    __syncthreads();

    // Phase 5: copy runs out coalesced; bucket-capacity overflow -> ovf.
    const int wave = tid >> 6;
    const int lane = tid & 63;
    for (int b = wave; b < NB; b += 8) {
        const int len = hist[b];
        const int st  = startS[b];
        const int gb  = gbase[b];
        for (int j = lane; j < len; j += 64) {
            const int pk = stage[st + j];
            const int gpos = gb + j;
            if (gpos < BCAP) {
                bkt[b * BCAP + gpos] = pk;
            } else {
                int oj = atomicAdd(ovf_cnt, 1);
                if (oj < OVF_CAP) ovf[oj] = make_int2(pk >> 8, b * 256 + (pk & 255));
            }
        }
    }
}

// ---------------------------------------------------------------------------
// R11 pass 2: owned CSR fill. One block per bucket; per-node cursors live in
// LDS (ds-side atomics, zero L2 atomic transactions); slot stores hit a
// private 32KB window. Writes cnt directly (no memset needed).
// ---------------------------------------------------------------------------
__global__ __launch_bounds__(512) void fill2_kernel(
    const int* __restrict__ bcnt, const int* __restrict__ bkt,
    int* __restrict__ cnt, int* __restrict__ slots,
    int* __restrict__ ovf_cnt, int2* __restrict__ ovf) {
    __shared__ int lcnt[256];
    const int b = blockIdx.x;
    const int tid = threadIdx.x;
    if (tid < 256) lcnt[tid] = 0;
    __syncthreads();
    int n = bcnt[b];
    if (n > BCAP) n = BCAP;
    for (int i = tid; i < n; i += 512) {
        const int pk = bkt[b * BCAP + i];
        const int dl = pk & 255;
        const int pos = atomicAdd(&lcnt[dl], 1);   // LDS atomic
        const int v = b * 256 + dl;
        if (pos < CAP) {
            slots[v * CAP + pos] = pk >> 8;
        } else {
            int j = atomicAdd(ovf_cnt, 1);
            if (j < OVF_CAP) ovf[j] = make_int2(pk >> 8, v);
        }
    }
    __syncthreads();
    if (tid < 256) {
        const int v = b * 256 + tid;
        if (v < N_NODES) cnt[v] = lcnt[tid];
    }
}

// ---------------------------------------------------------------------------
// Legacy region fill (mid tier only: ws too small for emb16/bucket path).
// ---------------------------------------------------------------------------
__global__ __launch_bounds__(256) void fill_kernel(
    const int* __restrict__ edge_src, const int* __restrict__ edge_dst,
    int* __restrict__ cnt, int* __restrict__ slots,
    int* __restrict__ ovf_cnt, int2* __restrict__ ovf) {
    const int r = blockIdx.x & (NR - 1);
    if (r == 7) return;
    const int slice = blockIdx.x >> 3;
    const int base_e = slice * SLICE_EDGES + threadIdx.x * 8;
    if (base_e >= N_EDGES) return;
    const vint4* s4 = (const vint4*)(edge_src + base_e);
    const vint4* d4 = (const vint4*)(edge_dst + base_e);
    vint4 a0 = __builtin_nontemporal_load(s4);
    vint4 a1 = __builtin_nontemporal_load(s4 + 1);
    vint4 b0 = __builtin_nontemporal_load(d4);
    vint4 b1 = __builtin_nontemporal_load(d4 + 1);
    int ss[8] = {a0.x, a0.y, a0.z, a0.w, a1.x, a1.y, a1.z, a1.w};
    int dd[8] = {b0.x, b0.y, b0.z, b0.w, b1.x, b1.y, b1.z, b1.w};
    int pos[8];
#pragma unroll
    for (int i = 0; i < 8; ++i) {
        pos[i] = ((dd[i] >> 14) == r) ? atomicAdd(&cnt[dd[i]], 1) : -1;
    }
#pragma unroll
    for (int i = 0; i < 8; ++i) {
        if (pos[i] >= 0 && pos[i] < CAP) slots[dd[i] * CAP + pos[i]] = ss[i];
    }
#pragma unroll
    for (int i = 0; i < 8; ++i) {
        if (pos[i] >= CAP) {
            int j = atomicAdd(ovf_cnt, 1);
            if (j < OVF_CAP) ovf[j] = make_int2(ss[i], dd[i]);
        }
    }
}

// ---------------------------------------------------------------------------
// Atomic-free gather, bf16 emb (R10-proven). One wave per node; q=lane>>4
// picks slot e+q, c=lane&15 picks a 4-elem column chunk; butterfly over q;
// q==0 stores f32 acc.
// ---------------------------------------------------------------------------
__global__ __launch_bounds__(256) void gather16_kernel(
    const short* __restrict__ emb16, const int* __restrict__ cnt,
    const int* __restrict__ slots, float* __restrict__ acc) {
    const int lane = threadIdx.x & 63;
    const int wave = threadIdx.x >> 6;
    const int v = blockIdx.x * 4 + wave;
    const int q = lane >> 4;
    const int c = lane & 15;
    int deg = cnt[v];
    if (deg > CAP) deg = CAP;
    const int si = slots[v * CAP + (lane & (CAP - 1))];

    float4 sum = make_float4(0.f, 0.f, 0.f, 0.f);
    for (int e = 0; e < deg; e += 4) {
        const int idx = e + q;
        const int s = __shfl(si, idx & (CAP - 1));
        if (idx < deg) {
            s16x4 a = *(const s16x4*)&emb16[s * D + c * 4];
            sum.x += bf2f(a.x);
            sum.y += bf2f(a.y);
            sum.z += bf2f(a.z);
            sum.w += bf2f(a.w);
        }
    }
#pragma unroll
    for (int off = 16; off < 64; off <<= 1) {
        sum.x += __shfl_xor(sum.x, off);
        sum.y += __shfl_xor(sum.y, off);
        sum.z += __shfl_xor(sum.z, off);
        sum.w += __shfl_xor(sum.w, off);
    }
    if (q == 0) {
        ((float4*)acc)[v * 16 + c] = sum;
    }
}

// f32 fallback gather (mid tier, ws too small for emb16).
__global__ __launch_bounds__(256) void gather_kernel(
    const float* __restrict__ emb, const int* __restrict__ cnt,
    const int* __restrict__ slots, float* __restrict__ acc) {
    const int lane = threadIdx.x & 63;
    const int wave = threadIdx.x >> 6;
    const int v = blockIdx.x * 4 + wave;
    const int q  = lane >> 4;
    const int c4 = lane & 15;
    int deg = cnt[v];
    if (deg > CAP) deg = CAP;
    const int si = slots[v * CAP + (lane & (CAP - 1))];
    const float4* emb4 = (const float4*)emb;

    float4 sum = make_float4(0.f, 0.f, 0.f, 0.f);
    for (int e = 0; e < deg; e += 4) {
        const int idx = e + q;
        const int s = __shfl(si, idx & (CAP - 1));
        if (idx < deg) {
            float4 a = emb4[s * 16 + c4];
            sum.x += a.x; sum.y += a.y; sum.z += a.z; sum.w += a.w;
        }
    }
#pragma unroll
    for (int off = 16; off < 64; off <<= 1) {
        sum.x += __shfl_xor(sum.x, off);
        sum.y += __shfl_xor(sum.y, off);
        sum.z += __shfl_xor(sum.z, off);
        sum.w += __shfl_xor(sum.w, off);
    }
    if (q == 0) {
        ((float4*)acc)[v * 16 + c4] = sum;
    }
}

// Overflow edges (a handful): parallel, adds into acc AFTER gather.
__global__ __launch_bounds__(256) void ovf_kernel(
    const float* __restrict__ emb, const int* __restrict__ ovf_cnt,
    const int2* __restrict__ ovf, float* __restrict__ acc) {
    int n = *ovf_cnt;
    if (n > OVF_CAP) n = OVF_CAP;
    const int lane = threadIdx.x & 63;
    const int wv = (blockIdx.x * 256 + threadIdx.x) >> 6;
    const int nwaves = (gridDim.x * 256) >> 6;
    for (int i = wv; i < n; i += nwaves) {
        int2 e = ovf[i];
        unsafeAtomicAdd(&acc[e.y * D + lane], emb[e.x * D + lane]);
    }
}

// Fallback scatter (only if ws too small).
__global__ __launch_bounds__(256) void scatter_kernel(
    const float* __restrict__ emb,
    const int* __restrict__ edge_src, const int* __restrict__ edge_dst,
    float* __restrict__ acc) {
    int gid = blockIdx.x * 256 + threadIdx.x;
    int e = gid >> 6;
    int c = gid & 63;
    unsafeAtomicAdd(&acc[edge_dst[e] * D + c], emb[edge_src[e] * D + c]);
}

// ---------------------------------------------------------------------------
// Final pass, MFMA. z = [feat|nbr] @ [W1|W2]^T, K=128, mfma_f32_16x16x32_bf16
// (4 k-steps). W fragments hoisted into 64 VGPRs once per block; per 16-node
// strip a wave issues 4 A-frag reads + 16 MFMAs. Fragment layouts
// (m89/m120-verified): a-operand A[m=lane&15][k=quad*8+j] -> m is D's ROW;
// b-operand B[n=lane&15][k] -> n is D's COL; C/D col=lane&15, row=quad*4+reg.
// Bias+ReLU in C-layout, masked for the ragged tail tile, then shfl+LDS
// reduce -> per-block partials.
// ---------------------------------------------------------------------------
__global__ __launch_bounds__(256) void final_kernel(
    const float* __restrict__ feat, const float* __restrict__ acc,
    const float* __restrict__ W1, const float* __restrict__ b1,
    const float* __restrict__ W2, const float* __restrict__ b2,
    float* __restrict__ partials) {
    __shared__ short A_s[64 * ASTRIDE];  // [node][feat(0..63)|nbr(64..127)] bf16
    __shared__ short W_s[64 * ASTRIDE];  // [o][W1(0..63)|W2(64..127)] bf16
    __shared__ float red[4][64];

    const int tid  = threadIdx.x;
    const int lane = tid & 63;
    const int wave = tid >> 6;
    const int quad = lane >> 4;
    const int col  = lane & 15;
    const int node0 = blockIdx.x * 64;

    float bias[4];
#pragma unroll
    for (int nb = 0; nb < 4; ++nb) {
        const int o = nb * 16 + col;
        bias[nb] = b1[o] + b2[o];
    }

    // Stage W (bf16): 1024 float4 per matrix, 4 per thread, coalesced.
    {
        const float4* W1v = (const float4*)W1;
        const float4* W2v = (const float4*)W2;
#pragma unroll
        for (int i = 0; i < 4; ++i) {
            const int flat = tid + i * 256;   // 0..1023
            const int row = flat >> 4, c4 = flat & 15;
            *(s16x4*)&W_s[row * ASTRIDE + c4 * 4]      = f2bf4(W1v[flat]);
            *(s16x4*)&W_s[row * ASTRIDE + 64 + c4 * 4] = f2bf4(W2v[flat]);
        }
    }

    // Stage A tile (bf16): feat + nbr rows for nodes node0..node0+63.
    {
        const float4* fv = (const float4*)feat;
        const float4* av = (const float4*)acc;
#pragma unroll
        for (int i = 0; i < 4; ++i) {
            const int flat = tid + i * 256;
            const int row = flat >> 4, c4 = flat & 15;
            const int node = node0 + row;
            float4 f = make_float4(0.f, 0.f, 0.f, 0.f);
            float4 n = make_float4(0.f, 0.f, 0.f, 0.f);
            if (node < N_NODES) {
                f = fv[(size_t)node * 16 + c4];
                n = av[(size_t)node * 16 + c4];
            }
            *(s16x4*)&A_s[row * ASTRIDE + c4 * 4]      = f2bf4(f);
            *(s16x4*)&A_s[row * ASTRIDE + 64 + c4 * 4] = f2bf4(n);
        }
    }
    __syncthreads();

    // Hoist all 16 B-fragments (4 output-blocks x 4 k-steps) into VGPRs.
    bf16x8 Bf[4][4];
#pragma unroll
    for (int nb = 0; nb < 4; ++nb)
#pragma unroll
        for (int ks = 0; ks < 4; ++ks)
            Bf[nb][ks] = __builtin_bit_cast(bf16x8,
                *(const s16x8*)&W_s[(nb * 16 + col) * ASTRIDE + ks * 32 + quad * 8]);

    f32x4 C[4];
#pragma unroll
    for (int nb = 0; nb < 4; ++nb) C[nb] = (f32x4){0.f, 0.f, 0.f, 0.f};
#pragma unroll
    for (int ks = 0; ks < 4; ++ks) {
        const bf16x8 Af = __builtin_bit_cast(bf16x8,
            *(const s16x8*)&A_s[(wave * 16 + col) * ASTRIDE + ks * 32 + quad * 8]);
#pragma unroll
        for (int nb = 0; nb < 4; ++nb)
            C[nb] = __builtin_amdgcn_mfma_f32_16x16x32_bf16(Af, Bf[nb][ks],
                                                            C[nb], 0, 0, 0);
    }

    // Epilogue: bias + ReLU per element (C-layout), mask OOB nodes, column
    // sums via shfl over quads, cross-wave combine in LDS.
    float sums[4] = {0.f, 0.f, 0.f, 0.f};
#pragma unroll
    for (int nb = 0; nb < 4; ++nb) {
#pragma unroll
        for (int reg = 0; reg < 4; ++reg) {
            const int node = node0 + wave * 16 + quad * 4 + reg;
            float u = C[nb][reg] + bias[nb];
            u = (u > 0.f) ? u : 0.f;
            if (node < N_NODES) sums[nb] += u;
        }
        sums[nb] += __shfl_xor(sums[nb], 16);
        sums[nb] += __shfl_xor(sums[nb], 32);
        if (lane < 16) red[wave][nb * 16 + lane] = sums[nb];
    }
    __syncthreads();
    if (tid < 64) {
        partials[blockIdx.x * 64 + tid] =
            red[0][tid] + red[1][tid] + red[2][tid] + red[3][tid];
    }
}

// ---------------------------------------------------------------------------
// Two-stage partials reduction (R9-proven).
// ---------------------------------------------------------------------------
__global__ __launch_bounds__(256) void reduce1_kernel(
    const float* __restrict__ partials, float* __restrict__ part2) {
    __shared__ float red[4][64];
    const int col = threadIdx.x & 63;
    const int seg = threadIdx.x >> 6;
    const int r0 = blockIdx.x * R1_ROWS;
    int r1 = r0 + R1_ROWS;
    if (r1 > N_TILES) r1 = N_TILES;
    float s = 0.f;
    for (int r = r0 + seg; r < r1; r += 4) s += partials[r * 64 + col];
    red[seg][col] = s;
    __syncthreads();
    if (seg == 0) {
        part2[blockIdx.x * 64 + col] =
            red[0][col] + red[1][col] + red[2][col] + red[3][col];
    }
}

__global__ __launch_bounds__(256) void reduce2_kernel(
    const float* __restrict__ part2, float* __restrict__ out) {
    __shared__ float red[4][64];
    const int col = threadIdx.x & 63;
    const int seg = threadIdx.x >> 6;
    float s = 0.f;
    for (int r = seg; r < R1_BLOCKS; r += 4) s += part2[r * 64 + col];
    red[seg][col] = s;
    __syncthreads();
    if (seg == 0) {
        out[col] = red[0][col] + red[1][col] + red[2][col] + red[3][col];
    }
}

extern "C" void kernel_launch(void* const* d_in, const int* in_sizes, int n_in,
                              void* d_out, int out_size, void* d_ws, size_t ws_size,
                              hipStream_t stream) {
    const float* feat = (const float*)d_in[0];
    const float* emb  = (const float*)d_in[1];
    const float* W1   = (const float*)d_in[2];
    const float* b1   = (const float*)d_in[3];
    const float* W2   = (const float*)d_in[4];
    const float* b2   = (const float*)d_in[5];
    const int* edge_src = (const int*)d_in[6];
    const int* edge_dst = (const int*)d_in[7];
    float* out = (float*)d_out;
    char* ws = (char*)d_ws;

    if (ws_size >= (size_t)WS_NEEDED16) {
        // R11 bucket path. Aliases: bkt lives in acc's space (dead until
        // gather16 overwrites all of acc); bcnt lives in partials' space
        // (dead until final_kernel).
        int*   cnt      = (int*)ws;
        int*   slots    = (int*)(ws + WS_SLOTS_OFF);
        float* acc      = (float*)(ws + WS_ACC_OFF);
        int*   bkt      = (int*)(ws + WS_ACC_OFF);
        int*   ovf_cnt  = (int*)(ws + WS_OVFC_OFF);
        int2*  ovf      = (int2*)(ws + WS_OVF_OFF);
        float* partials = (float*)(ws + WS_PART_OFF);
        int*   bcnt     = (int*)(ws + WS_PART_OFF);
        float* part2    = (float*)(ws + WS_PART2_OFF);
        short* emb16    = (short*)(ws + WS_EMB16_OFF);

        (void)hipMemsetAsync(ovf_cnt, 0, sizeof(int), stream);
        (void)hipMemsetAsync(bcnt, 0, NB * sizeof(int), stream);

        part_kernel<<<P1_BLOCKS + CVT_BLOCKS, 512, 0, stream>>>(
            edge_src, edge_dst, bcnt, bkt, ovf_cnt, ovf, emb, emb16);
        fill2_kernel<<<NB, 512, 0, stream>>>(bcnt, bkt, cnt, slots,
                                             ovf_cnt, ovf);
        gather16_kernel<<<N_NODES / 4, 256, 0, stream>>>(emb16, cnt, slots, acc);
        ovf_kernel<<<16, 256, 0, stream>>>(emb, ovf_cnt, ovf, acc);

        final_kernel<<<N_TILES, 256, 0, stream>>>(feat, acc, W1, b1, W2, b2,
                                                  partials);
        reduce1_kernel<<<R1_BLOCKS, 256, 0, stream>>>(partials, part2);
        reduce2_kernel<<<1, 256, 0, stream>>>(part2, out);
    } else if (ws_size >= (size_t)WS_NEEDED) {
        int*   cnt      = (int*)ws;
        int*   slots    = (int*)(ws + WS_SLOTS_OFF);
        float* acc      = (float*)(ws + WS_ACC_OFF);
        int*   ovf_cnt  = (int*)(ws + WS_OVFC_OFF);
        int2*  ovf      = (int2*)(ws + WS_OVF_OFF);
        float* partials = (float*)(ws + WS_PART_OFF);
        float* part2    = (float*)(ws + WS_PART2_OFF);

        (void)hipMemsetAsync(cnt, 0, N_NODES * sizeof(int), stream);
        (void)hipMemsetAsync(ovf_cnt, 0, sizeof(int), stream);

        fill_kernel<<<NR * N_SLICES, 256, 0, stream>>>(edge_src, edge_dst,
                                                       cnt, slots, ovf_cnt, ovf);
        gather_kernel<<<N_NODES / 4, 256, 0, stream>>>(emb, cnt, slots, acc);
        ovf_kernel<<<16, 256, 0, stream>>>(emb, ovf_cnt, ovf, acc);

        final_kernel<<<N_TILES, 256, 0, stream>>>(feat, acc, W1, b1, W2, b2,
                                                  partials);
        reduce1_kernel<<<R1_BLOCKS, 256, 0, stream>>>(partials, part2);
        reduce2_kernel<<<1, 256, 0, stream>>>(part2, out);
    } else {
        // Fallback: atomic scatter (correct but slow).
        float* acc = (float*)ws;
        (void)hipMemsetAsync(acc, 0, (size_t)N_NODES * D * sizeof(float), stream);
        scatter_kernel<<<(N_EDGES * 64) / 256, 256, 0, stream>>>(emb, edge_src,
                                                                 edge_dst, acc);
        float* partials = (float*)(ws + (size_t)N_NODES * D * sizeof(float));
        float* part2    = partials + (size_t)N_TILES * 64;
        final_kernel<<<N_TILES, 256, 0, stream>>>(feat, acc, W1, b1, W2, b2,
                                                  partials);
        reduce1_kernel<<<R1_BLOCKS, 256, 0, stream>>>(partials, part2);
        reduce2_kernel<<<1, 256, 0, stream>>>(part2, out);
    }
}